// Round 4
// baseline (422.546 us; speedup 1.0000x reference)
//
#include <hip/hip_runtime.h>
#include <cstdint>

// ---------------------------------------------------------------------------
// PaddedSoftmaxSHCSA: y = softmax(mask(scale * (xW+b)_q @ (xW+b)_k^T)) @ (xW+b)_v
// T=4096, C=2048, NF=2048, 3*NF=6144. fp32 in/out, bf16 MFMA compute.
//
// Round 4 changes:
//  * GEMM core moved to mfma_f32_32x32x16_bf16: 8 MFMA/iter (was 16) at the
//    same FLOP — higher ceiling (2495 vs 2075 TF), half the MFMA issue slots,
//    all 8 fragments preloaded (R3's af-streaming serialized deps; reverted).
//  * pv grid remapped so same-CU block pairs (i, i+256 under round-robin)
//    get complementary m-tiles (m, 31-m): per-CU K-work uniform at 132 iters
//    (was 8..256 — worst CU 256 iters while most idled).
//  * sc grid = 528 triangular blocks only (decode m,n from flat idx) instead
//    of 1024 with 496 immediate-return no-ops.
//  * LDS XOR swizzle retained (verified 1.26e7 -> 0 bank conflicts); the
//    32x32 fragment read pattern is also 2-way (free) under the same swizzle.
// ---------------------------------------------------------------------------

#define T_DIM 4096
#define C_DIM 2048
#define NF    2048
#define N3    6144
#define NEGV  (-1e30f)

typedef __bf16 bf16x8 __attribute__((ext_vector_type(8)));
typedef __bf16 bf16x4 __attribute__((ext_vector_type(4)));
typedef float  f32x16 __attribute__((ext_vector_type(16)));

__device__ __forceinline__ void async_cp16(const void* g, void* l) {
    __builtin_amdgcn_global_load_lds(
        reinterpret_cast<const __attribute__((address_space(1))) unsigned int*>(
            reinterpret_cast<uintptr_t>(g)),
        reinterpret_cast<__attribute__((address_space(3))) unsigned int*>(
            reinterpret_cast<uintptr_t>(l)),
        16, 0, 0);
}

// Shared 128x128-tile GEMM K-loop: C[m0..+128, n0..+128] += A @ B^T
// A: (M x K) row-major, lda elems; B: (N x K) row-major, ldb elems.
// LDS layout XOR-swizzled: element (row, 8c+e) at row*32 + (c^((row>>1)&3))*8+e.
// Wave tile 64x64 = 2x2 blocks of 32x32; mfma_f32_32x32x16_bf16, K=32/iter.
__device__ __forceinline__ void gemm_loop(const __bf16* A, const __bf16* B,
                                          int lda, int ldb, int m0, int n0,
                                          int kiters, __bf16* As, __bf16* Bs,
                                          f32x16 (&acc)[2][2]) {
    const int t    = threadIdx.x;          // 0..255
    const int wv   = t >> 6;               // wave 0..3
    const int lane = t & 63;
    const int srow = t >> 2;               // staging row 0..63
    // staging lane's LDS slot holds phys chunk (t&3) of row srow -> fetch the
    // logical chunk that maps there (global_load_lds dest is fixed).
    const int scol = (((t & 3) ^ ((srow >> 1) & 3)) << 3);
    const int wm   = (wv >> 1) << 6;       // wave m offset 0/64
    const int wn   = (wv & 1) << 6;        // wave n offset 0/64
    const int lr   = lane & 31;            // row within a 32-block
    const int kh0  = lane >> 5;            // k-half select (A/B frag layout)
    const int swz  = (lr >> 1) & 3;        // 32/64 offsets preserve (row>>1)&3

    const __bf16* ga = A + (size_t)(m0 + srow) * lda + scol;
    const __bf16* gb = B + (size_t)(n0 + srow) * ldb + scol;

    // physical 16B-chunk column for frag (kh): chunk = (kh0 | kh<<1) ^ swz
    const int rc0 = ((kh0 ^ swz) << 3);
    const int rc1 = (((kh0 | 2) ^ swz) << 3);

    for (int kk = 0; kk < kiters; ++kk) {
        // stage A tile (128x32) and B tile (128x32); each issue = 4KB (64 rows)
        async_cp16(ga,                       &As[wv * 512]);
        async_cp16(ga + (size_t)64 * lda,    &As[wv * 512 + 2048]);
        async_cp16(gb,                       &Bs[wv * 512]);
        async_cp16(gb + (size_t)64 * ldb,    &Bs[wv * 512 + 2048]);
        ga += 32; gb += 32;
        __syncthreads();   // vmcnt(0) drain + barrier

        bf16x8 af[2][2], bf[2][2];
#pragma unroll
        for (int mi = 0; mi < 2; ++mi) {
            const int row = (wm + mi * 32 + lr) * 32;
            af[mi][0] = *(const bf16x8*)&As[row + rc0];
            af[mi][1] = *(const bf16x8*)&As[row + rc1];
        }
#pragma unroll
        for (int ni = 0; ni < 2; ++ni) {
            const int row = (wn + ni * 32 + lr) * 32;
            bf[ni][0] = *(const bf16x8*)&Bs[row + rc0];
            bf[ni][1] = *(const bf16x8*)&Bs[row + rc1];
        }
#pragma unroll
        for (int kh = 0; kh < 2; ++kh)
#pragma unroll
            for (int mi = 0; mi < 2; ++mi)
#pragma unroll
                for (int ni = 0; ni < 2; ++ni)
                    acc[mi][ni] = __builtin_amdgcn_mfma_f32_32x32x16_bf16(
                        af[mi][kh], bf[ni][kh], acc[mi][ni], 0, 0, 0);
        __syncthreads();   // protect LDS before next-iter staging overwrite
    }
}

// ---------------- 1. cast x -> bf16 ----------------
__global__ void cast_x_kernel(const float* __restrict__ x,
                              __bf16* __restrict__ xb, int n4) {
    int stride = gridDim.x * blockDim.x;
    for (int i = blockIdx.x * blockDim.x + threadIdx.x; i < n4; i += stride) {
        float4 v = ((const float4*)x)[i];
        bf16x4 o;
        o[0] = (__bf16)v.x; o[1] = (__bf16)v.y;
        o[2] = (__bf16)v.z; o[3] = (__bf16)v.w;
        ((bf16x4*)xb)[i] = o;
    }
}

// ---------------- 2. transpose-cast W (2048x6144) -> Wt (6144x2048) --------
__global__ void transpose_w_kernel(const float* __restrict__ W,
                                   __bf16* __restrict__ Wt) {
    __shared__ float tile[32][33];
    int bx = blockIdx.x * 32;  // W col / Wt row
    int by = blockIdx.y * 32;  // W row / Wt col
    int tx = threadIdx.x, ty = threadIdx.y;  // (32,8)
#pragma unroll
    for (int i = 0; i < 32; i += 8)
        tile[ty + i][tx] = W[(size_t)(by + ty + i) * N3 + bx + tx];
    __syncthreads();
#pragma unroll
    for (int i = 0; i < 32; i += 8)
        Wt[(size_t)(bx + ty + i) * C_DIM + by + tx] = (__bf16)tile[tx][ty + i];
}

// epilogue index helpers for 32x32 C/D: col=lane&31, row=(r&3)+8*(r>>2)+4*(lane>>5)
#define EPILOG_SETUP()                                    \
    const int t = threadIdx.x, wv = t >> 6, lane = t & 63; \
    const int wm = (wv >> 1) << 6, wn = (wv & 1) << 6;     \
    const int lr = lane & 31, rr = (lane >> 5) << 2

// ---------------- 3. QKV GEMM ----------------
__global__ void __launch_bounds__(256, 4)
qkv_gemm_kernel(const __bf16* __restrict__ xb, const __bf16* __restrict__ Wt,
                const float* __restrict__ bias, __bf16* __restrict__ qb,
                __bf16* __restrict__ kb, __bf16* __restrict__ vT) {
    __shared__ __bf16 As[128 * 32];
    __shared__ __bf16 Bs[128 * 32];
    f32x16 acc[2][2] = {};
    const int m0 = blockIdx.x * 128, n0 = blockIdx.y * 128;
    gemm_loop(xb, Wt, C_DIM, C_DIM, m0, n0, C_DIM / 32, As, Bs, acc);

    EPILOG_SETUP();
#pragma unroll
    for (int mi = 0; mi < 2; ++mi)
#pragma unroll
        for (int ni = 0; ni < 2; ++ni) {
            int col = n0 + wn + ni * 32 + lr;
            float bv = bias[col];
#pragma unroll
            for (int r = 0; r < 16; ++r) {
                int row = m0 + wm + mi * 32 + (r & 3) + ((r >> 2) << 3) + rr;
                float val = acc[mi][ni][r] + bv;
                if (col < NF)
                    qb[(size_t)row * NF + col] = (__bf16)val;
                else if (col < 2 * NF)
                    kb[(size_t)row * NF + (col - NF)] = (__bf16)val;
                else
                    vT[(size_t)(col - 2 * NF) * T_DIM + row] = (__bf16)val;
            }
        }
}

// ---------------- 4. S = scale * q @ k^T (bf16; mask applied in softmax) ---
// Grid = 528 lower-triangle 128x128 tiles (triangular decode).
__global__ void __launch_bounds__(256, 4)
sc_gemm_kernel(const __bf16* __restrict__ qb, const __bf16* __restrict__ kb,
               __bf16* __restrict__ S) {
    int i = blockIdx.x;
    int mt = (int)((sqrtf(8.0f * (float)i + 1.0f) - 1.0f) * 0.5f);
    while ((mt + 1) * (mt + 2) / 2 <= i) ++mt;
    while (mt * (mt + 1) / 2 > i) --mt;
    int nt = i - mt * (mt + 1) / 2;
    const int m0 = mt * 128, n0 = nt * 128;

    __shared__ __bf16 As[128 * 32];
    __shared__ __bf16 Bs[128 * 32];
    f32x16 acc[2][2] = {};
    gemm_loop(qb, kb, NF, NF, m0, n0, NF / 32, As, Bs, acc);

    const float scale = 0.022097086912079608f;  // 1/sqrt(2048)
    EPILOG_SETUP();
#pragma unroll
    for (int mi = 0; mi < 2; ++mi)
#pragma unroll
        for (int ni = 0; ni < 2; ++ni) {
            int j = n0 + wn + ni * 32 + lr;
#pragma unroll
            for (int r = 0; r < 16; ++r) {
                int row = m0 + wm + mi * 32 + (r & 3) + ((r >> 2) << 3) + rr;
                S[(size_t)row * T_DIM + j] = (__bf16)(acc[mi][ni][r] * scale);
            }
        }
}

// ---------------- 5. row softmax (analytic mask), bf16 in -> bf16 out ------
__global__ void __launch_bounds__(256)
softmax_kernel(const __bf16* __restrict__ S, __bf16* __restrict__ P,
               const int* __restrict__ npadd_p) {
    const int row = blockIdx.x;
    const int t = threadIdx.x, lane = t & 63, wv = t >> 6;
    const int npadd = *npadd_p;
    __bf16* prow = P + (size_t)row * T_DIM;

    if (row < npadd) {  // padding row: p == 0
        float4 z = make_float4(0.f, 0.f, 0.f, 0.f);
        float4* p4 = (float4*)prow;  // 4096 bf16 = 512 x 16B
        for (int i = t; i < 512; i += 256) p4[i] = z;
        return;
    }

    const __bf16* srow = S + (size_t)row * T_DIM;
    float vals[16];
#pragma unroll
    for (int k = 0; k < 16; ++k) vals[k] = NEGV;
    float mx = NEGV;
#pragma unroll
    for (int c = 0; c < 4; ++c) {
        if (c * 1024 > row) break;  // row-uniform: no divergence
        int j0 = c * 1024 + t * 4;
        bf16x4 v = ((const bf16x4*)srow)[c * 256 + t];
        vals[c * 4 + 0] = (j0 + 0 >= npadd && j0 + 0 <= row) ? (float)v[0] : NEGV;
        vals[c * 4 + 1] = (j0 + 1 >= npadd && j0 + 1 <= row) ? (float)v[1] : NEGV;
        vals[c * 4 + 2] = (j0 + 2 >= npadd && j0 + 2 <= row) ? (float)v[2] : NEGV;
        vals[c * 4 + 3] = (j0 + 3 >= npadd && j0 + 3 <= row) ? (float)v[3] : NEGV;
        mx = fmaxf(mx, fmaxf(fmaxf(vals[c * 4 + 0], vals[c * 4 + 1]),
                             fmaxf(vals[c * 4 + 2], vals[c * 4 + 3])));
    }
    __shared__ float wred[8];
#pragma unroll
    for (int o = 32; o > 0; o >>= 1) mx = fmaxf(mx, __shfl_xor(mx, o));
    if (lane == 0) wred[wv] = mx;
    __syncthreads();
    mx = fmaxf(fmaxf(wred[0], wred[1]), fmaxf(wred[2], wred[3]));

    float sm = 0.f;
#pragma unroll
    for (int k = 0; k < 16; ++k) {
        vals[k] = exp2f((vals[k] - mx) * 1.4426950408889634f);
        sm += vals[k];
    }
#pragma unroll
    for (int o = 32; o > 0; o >>= 1) sm += __shfl_xor(sm, o);
    if (lane == 0) wred[4 + wv] = sm;
    __syncthreads();
    sm = (wred[4] + wred[5]) + (wred[6] + wred[7]);
    float inv = 1.0f / sm;

#pragma unroll
    for (int c = 0; c < 4; ++c) {
        bf16x4 o;
        o[0] = (__bf16)(vals[c * 4 + 0] * inv);
        o[1] = (__bf16)(vals[c * 4 + 1] * inv);
        o[2] = (__bf16)(vals[c * 4 + 2] * inv);
        o[3] = (__bf16)(vals[c * 4 + 3] * inv);
        ((bf16x4*)prow)[c * 256 + t] = o;
    }
}

// ---------------- 6. y = P @ V ----------------
// Flat grid 512; remapped so same-CU pairs (idx, idx+256 under round-robin
// dispatch) get complementary m-tiles (m, 31-m) -> uniform 132 K-iters/CU.
__global__ void __launch_bounds__(256, 4)
pv_gemm_kernel(const __bf16* __restrict__ P, const __bf16* __restrict__ vT,
               float* __restrict__ out) {
    const int idx = blockIdx.x;
    const int j = idx & 255, h = idx >> 8;
    int mt = j >> 3; if (h) mt = 31 - mt;
    const int nt = (j & 7) + (h << 3);
    const int m0 = mt * 128, n0 = nt * 128;
    const int kiters = (mt + 1) * 4;  // causal: P[i][j]=0 for j>i

    __shared__ __bf16 As[128 * 32];
    __shared__ __bf16 Bs[128 * 32];
    f32x16 acc[2][2] = {};
    gemm_loop(P, vT, T_DIM, T_DIM, m0, n0, kiters, As, Bs, acc);

    EPILOG_SETUP();
#pragma unroll
    for (int mi = 0; mi < 2; ++mi)
#pragma unroll
        for (int ni = 0; ni < 2; ++ni) {
            int col = n0 + wn + ni * 32 + lr;
#pragma unroll
            for (int r = 0; r < 16; ++r) {
                int row = m0 + wm + mi * 32 + (r & 3) + ((r >> 2) << 3) + rr;
                out[(size_t)row * NF + col] = acc[mi][ni][r];
            }
        }
}

extern "C" void kernel_launch(void* const* d_in, const int* in_sizes, int n_in,
                              void* d_out, int out_size, void* d_ws,
                              size_t ws_size, hipStream_t stream) {
    const float* x = (const float*)d_in[0];
    const float* W = (const float*)d_in[1];
    const float* b = (const float*)d_in[2];
    const int* npadd = (const int*)d_in[3];
    float* out = (float*)d_out;

    char* ws = (char*)d_ws;
    // layout (120 MB used):
    __bf16* xb = (__bf16*)(ws);                          // 16 MB [0,16)
    __bf16* Wt = (__bf16*)(ws + (16ull << 20));          // 24 MB [16,40)
    __bf16* qb = (__bf16*)(ws + (40ull << 20));          // 16 MB [40,56)
    __bf16* kb = (__bf16*)(ws + (56ull << 20));          // 16 MB [56,72)
    __bf16* vT = (__bf16*)(ws + (72ull << 20));          // 16 MB [72,88)
    __bf16* S  = (__bf16*)(ws + (88ull << 20));          // 32 MB [88,120)
    __bf16* P  = (__bf16*)(ws + (40ull << 20));          // 32 MB reuse qb+kb

    cast_x_kernel<<<2048, 256, 0, stream>>>(x, xb, (T_DIM * C_DIM) / 4);
    transpose_w_kernel<<<dim3(N3 / 32, C_DIM / 32), dim3(32, 8), 0, stream>>>(W, Wt);
    qkv_gemm_kernel<<<dim3(T_DIM / 128, N3 / 128), 256, 0, stream>>>(xb, Wt, b,
                                                                     qb, kb, vT);
    sc_gemm_kernel<<<528, 256, 0, stream>>>(qb, kb, S);
    softmax_kernel<<<T_DIM, 256, 0, stream>>>(S, P, npadd);
    pv_gemm_kernel<<<512, 256, 0, stream>>>(P, vT, out);
}

// Round 5
// 416.875 us; speedup vs baseline: 1.0136x; 1.0136x over previous
//
#include <hip/hip_runtime.h>
#include <cstdint>

// ---------------------------------------------------------------------------
// PaddedSoftmaxSHCSA: y = softmax(mask(scale * (xW+b)_q @ (xW+b)_k^T)) @ (xW+b)_v
// T=4096, C=2048, NF=2048, 3*NF=6144. fp32 in/out, bf16 MFMA compute.
//
// Round 5 = recombination of measured-good pieces:
//  * GEMM core: R2's 16x16x32 MFMA, all 8 fragments preloaded, XOR-swizzled
//    LDS (measured 0 bank conflicts, QKV 140 us). R4's 32x32 shape REVERTED:
//    its fragment phasing re-triggered 1.26e7 conflicts (+4 cyc/ds_read).
//  * sc grid: 528 lower-triangle tiles only (from R4).
//  * pv grid: flat 512, complementary-pair mapping (mt, 31-mt) -> uniform
//    132 K-iters/CU (from R4; R3's x-major map had a 512-iter straggler CU).
//  * S stored bf16 (from R3).
// ---------------------------------------------------------------------------

#define T_DIM 4096
#define C_DIM 2048
#define NF    2048
#define N3    6144
#define NEGV  (-1e30f)

typedef __bf16 bf16x8 __attribute__((ext_vector_type(8)));
typedef __bf16 bf16x4 __attribute__((ext_vector_type(4)));
typedef float  f32x4  __attribute__((ext_vector_type(4)));

__device__ __forceinline__ void async_cp16(const void* g, void* l) {
    __builtin_amdgcn_global_load_lds(
        reinterpret_cast<const __attribute__((address_space(1))) unsigned int*>(
            reinterpret_cast<uintptr_t>(g)),
        reinterpret_cast<__attribute__((address_space(3))) unsigned int*>(
            reinterpret_cast<uintptr_t>(l)),
        16, 0, 0);
}

// Shared 128x128-tile GEMM K-loop: C[m0..+128, n0..+128] += A @ B^T
// A: (M x K) row-major, lda elems; B: (N x K) row-major, ldb elems.
// LDS layout XOR-swizzled: element (row, 8c+e) at row*32 + (c^((row>>1)&3))*8+e
// (verified: kills the 8-way conflict of the 64B-row-stride b128 pattern).
// 16x16x32 MFMA, wave tile 64x64 = 4x4 accs. DO NOT switch to 32x32x16 or
// stream A-fragments: both measured slower (R3: dep-chain serialization,
// R4: bank conflicts return).
__device__ __forceinline__ void gemm_loop(const __bf16* A, const __bf16* B,
                                          int lda, int ldb, int m0, int n0,
                                          int kiters, __bf16* As, __bf16* Bs,
                                          f32x4 (&acc)[4][4]) {
    const int t    = threadIdx.x;          // 0..255
    const int wv   = t >> 6;               // wave 0..3
    const int lane = t & 63;
    const int srow = t >> 2;               // staging row 0..63
    // lane's LDS slot holds phys chunk (t&3) of row srow -> fetch the logical
    // chunk that maps there (global_load_lds dest is fixed at base+lane*16).
    const int scol = (((t & 3) ^ ((srow >> 1) & 3)) << 3);
    const int wm   = (wv >> 1) << 6;       // wave m offset 0/64
    const int wn   = (wv & 1) << 6;        // wave n offset 0/64
    const int lrow = lane & 15;
    const int kc   = lane >> 4;            // logical 16B chunk 0..3
    const int swz  = (lrow >> 1) & 3;      // 16/32/64 row offsets preserve it
    const int rcol = ((kc ^ swz) << 3);    // physical column in LDS row

    const __bf16* ga = A + (size_t)(m0 + srow) * lda + scol;
    const __bf16* gb = B + (size_t)(n0 + srow) * ldb + scol;

    for (int kk = 0; kk < kiters; ++kk) {
        // stage A tile (128x32) and B tile (128x32); each issue = 4KB (64 rows)
        async_cp16(ga,                       &As[wv * 512]);
        async_cp16(ga + (size_t)64 * lda,    &As[wv * 512 + 2048]);
        async_cp16(gb,                       &Bs[wv * 512]);
        async_cp16(gb + (size_t)64 * ldb,    &Bs[wv * 512 + 2048]);
        ga += 32; gb += 32;
        __syncthreads();   // vmcnt(0) drain + barrier

        bf16x8 af[4], bfr[4];
#pragma unroll
        for (int mi = 0; mi < 4; ++mi)
            af[mi] = *(const bf16x8*)&As[(wm + mi * 16 + lrow) * 32 + rcol];
#pragma unroll
        for (int ni = 0; ni < 4; ++ni)
            bfr[ni] = *(const bf16x8*)&Bs[(wn + ni * 16 + lrow) * 32 + rcol];
#pragma unroll
        for (int mi = 0; mi < 4; ++mi)
#pragma unroll
            for (int ni = 0; ni < 4; ++ni)
                acc[mi][ni] = __builtin_amdgcn_mfma_f32_16x16x32_bf16(
                    af[mi], bfr[ni], acc[mi][ni], 0, 0, 0);
        __syncthreads();   // protect LDS before next-iter staging overwrite
    }
}

// ---------------- 1. cast x -> bf16 ----------------
__global__ void cast_x_kernel(const float* __restrict__ x,
                              __bf16* __restrict__ xb, int n4) {
    int stride = gridDim.x * blockDim.x;
    for (int i = blockIdx.x * blockDim.x + threadIdx.x; i < n4; i += stride) {
        float4 v = ((const float4*)x)[i];
        bf16x4 o;
        o[0] = (__bf16)v.x; o[1] = (__bf16)v.y;
        o[2] = (__bf16)v.z; o[3] = (__bf16)v.w;
        ((bf16x4*)xb)[i] = o;
    }
}

// ---------------- 2. transpose-cast W (2048x6144) -> Wt (6144x2048) --------
__global__ void transpose_w_kernel(const float* __restrict__ W,
                                   __bf16* __restrict__ Wt) {
    __shared__ float tile[32][33];
    int bx = blockIdx.x * 32;  // W col / Wt row
    int by = blockIdx.y * 32;  // W row / Wt col
    int tx = threadIdx.x, ty = threadIdx.y;  // (32,8)
#pragma unroll
    for (int i = 0; i < 32; i += 8)
        tile[ty + i][tx] = W[(size_t)(by + ty + i) * N3 + bx + tx];
    __syncthreads();
#pragma unroll
    for (int i = 0; i < 32; i += 8)
        Wt[(size_t)(bx + ty + i) * C_DIM + by + tx] = (__bf16)tile[tx][ty + i];
}

// epilogue helpers for 16x16 C/D: col=lane&15, row=(lane>>4)*4+r
#define EPILOG_SETUP()                                     \
    const int t = threadIdx.x, wv = t >> 6, lane = t & 63; \
    const int wm = (wv >> 1) << 6, wn = (wv & 1) << 6;     \
    const int rq = (lane >> 4) << 2, cn = lane & 15

// ---------------- 3. QKV GEMM ----------------
__global__ void __launch_bounds__(256)
qkv_gemm_kernel(const __bf16* __restrict__ xb, const __bf16* __restrict__ Wt,
                const float* __restrict__ bias, __bf16* __restrict__ qb,
                __bf16* __restrict__ kb, __bf16* __restrict__ vT) {
    __shared__ __bf16 As[128 * 32];
    __shared__ __bf16 Bs[128 * 32];
    f32x4 acc[4][4] = {};
    const int m0 = blockIdx.x * 128, n0 = blockIdx.y * 128;
    gemm_loop(xb, Wt, C_DIM, C_DIM, m0, n0, C_DIM / 32, As, Bs, acc);

    EPILOG_SETUP();
#pragma unroll
    for (int mi = 0; mi < 4; ++mi)
#pragma unroll
        for (int ni = 0; ni < 4; ++ni) {
            int col = n0 + wn + ni * 16 + cn;
            float bv = bias[col];
#pragma unroll
            for (int r = 0; r < 4; ++r) {
                int row = m0 + wm + mi * 16 + rq + r;
                float val = acc[mi][ni][r] + bv;
                if (col < NF)
                    qb[(size_t)row * NF + col] = (__bf16)val;
                else if (col < 2 * NF)
                    kb[(size_t)row * NF + (col - NF)] = (__bf16)val;
                else
                    vT[(size_t)(col - 2 * NF) * T_DIM + row] = (__bf16)val;
            }
        }
}

// ---------------- 4. S = scale * q @ k^T (bf16; mask applied in softmax) ---
// Grid = 528 lower-triangle 128x128 tiles (triangular decode).
__global__ void __launch_bounds__(256)
sc_gemm_kernel(const __bf16* __restrict__ qb, const __bf16* __restrict__ kb,
               __bf16* __restrict__ S) {
    int i = blockIdx.x;
    int mt = (int)((sqrtf(8.0f * (float)i + 1.0f) - 1.0f) * 0.5f);
    while ((mt + 1) * (mt + 2) / 2 <= i) ++mt;
    while (mt * (mt + 1) / 2 > i) --mt;
    int nt = i - mt * (mt + 1) / 2;
    const int m0 = mt * 128, n0 = nt * 128;

    __shared__ __bf16 As[128 * 32];
    __shared__ __bf16 Bs[128 * 32];
    f32x4 acc[4][4] = {};
    gemm_loop(qb, kb, NF, NF, m0, n0, NF / 32, As, Bs, acc);

    const float scale = 0.022097086912079608f;  // 1/sqrt(2048)
    EPILOG_SETUP();
#pragma unroll
    for (int mi = 0; mi < 4; ++mi)
#pragma unroll
        for (int ni = 0; ni < 4; ++ni) {
            int j = n0 + wn + ni * 16 + cn;
#pragma unroll
            for (int r = 0; r < 4; ++r) {
                int row = m0 + wm + mi * 16 + rq + r;
                S[(size_t)row * T_DIM + j] = (__bf16)(acc[mi][ni][r] * scale);
            }
        }
}

// ---------------- 5. row softmax (analytic mask), bf16 in -> bf16 out ------
__global__ void __launch_bounds__(256)
softmax_kernel(const __bf16* __restrict__ S, __bf16* __restrict__ P,
               const int* __restrict__ npadd_p) {
    const int row = blockIdx.x;
    const int t = threadIdx.x, lane = t & 63, wv = t >> 6;
    const int npadd = *npadd_p;
    __bf16* prow = P + (size_t)row * T_DIM;

    if (row < npadd) {  // padding row: p == 0
        float4 z = make_float4(0.f, 0.f, 0.f, 0.f);
        float4* p4 = (float4*)prow;  // 4096 bf16 = 512 x 16B
        for (int i = t; i < 512; i += 256) p4[i] = z;
        return;
    }

    const __bf16* srow = S + (size_t)row * T_DIM;
    float vals[16];
#pragma unroll
    for (int k = 0; k < 16; ++k) vals[k] = NEGV;
    float mx = NEGV;
#pragma unroll
    for (int c = 0; c < 4; ++c) {
        if (c * 1024 > row) break;  // row-uniform: no divergence
        int j0 = c * 1024 + t * 4;
        bf16x4 v = ((const bf16x4*)srow)[c * 256 + t];
        vals[c * 4 + 0] = (j0 + 0 >= npadd && j0 + 0 <= row) ? (float)v[0] : NEGV;
        vals[c * 4 + 1] = (j0 + 1 >= npadd && j0 + 1 <= row) ? (float)v[1] : NEGV;
        vals[c * 4 + 2] = (j0 + 2 >= npadd && j0 + 2 <= row) ? (float)v[2] : NEGV;
        vals[c * 4 + 3] = (j0 + 3 >= npadd && j0 + 3 <= row) ? (float)v[3] : NEGV;
        mx = fmaxf(mx, fmaxf(fmaxf(vals[c * 4 + 0], vals[c * 4 + 1]),
                             fmaxf(vals[c * 4 + 2], vals[c * 4 + 3])));
    }
    __shared__ float wred[8];
#pragma unroll
    for (int o = 32; o > 0; o >>= 1) mx = fmaxf(mx, __shfl_xor(mx, o));
    if (lane == 0) wred[wv] = mx;
    __syncthreads();
    mx = fmaxf(fmaxf(wred[0], wred[1]), fmaxf(wred[2], wred[3]));

    float sm = 0.f;
#pragma unroll
    for (int k = 0; k < 16; ++k) {
        vals[k] = exp2f((vals[k] - mx) * 1.4426950408889634f);
        sm += vals[k];
    }
#pragma unroll
    for (int o = 32; o > 0; o >>= 1) sm += __shfl_xor(sm, o);
    if (lane == 0) wred[4 + wv] = sm;
    __syncthreads();
    sm = (wred[4] + wred[5]) + (wred[6] + wred[7]);
    float inv = 1.0f / sm;

#pragma unroll
    for (int c = 0; c < 4; ++c) {
        bf16x4 o;
        o[0] = (__bf16)(vals[c * 4 + 0] * inv);
        o[1] = (__bf16)(vals[c * 4 + 1] * inv);
        o[2] = (__bf16)(vals[c * 4 + 2] * inv);
        o[3] = (__bf16)(vals[c * 4 + 3] * inv);
        ((bf16x4*)prow)[c * 256 + t] = o;
    }
}

// ---------------- 6. y = P @ V ----------------
// Flat grid 512; same-CU pairs (idx, idx+256 under round-robin dispatch)
// get complementary m-tiles (m, 31-m) -> uniform 132 K-iters/CU.
__global__ void __launch_bounds__(256)
pv_gemm_kernel(const __bf16* __restrict__ P, const __bf16* __restrict__ vT,
               float* __restrict__ out) {
    const int idx = blockIdx.x;
    const int j = idx & 255, h = idx >> 8;
    int mt = j >> 3; if (h) mt = 31 - mt;
    const int nt = (j & 7) + (h << 3);
    const int m0 = mt * 128, n0 = nt * 128;
    const int kiters = (mt + 1) * 4;  // causal: P[i][j]=0 for j>i

    __shared__ __bf16 As[128 * 32];
    __shared__ __bf16 Bs[128 * 32];
    f32x4 acc[4][4] = {};
    gemm_loop(P, vT, T_DIM, T_DIM, m0, n0, kiters, As, Bs, acc);

    EPILOG_SETUP();
#pragma unroll
    for (int mi = 0; mi < 4; ++mi)
#pragma unroll
        for (int ni = 0; ni < 4; ++ni) {
            int col = n0 + wn + ni * 16 + cn;
#pragma unroll
            for (int r = 0; r < 4; ++r) {
                int row = m0 + wm + mi * 16 + rq + r;
                out[(size_t)row * NF + col] = acc[mi][ni][r];
            }
        }
}

extern "C" void kernel_launch(void* const* d_in, const int* in_sizes, int n_in,
                              void* d_out, int out_size, void* d_ws,
                              size_t ws_size, hipStream_t stream) {
    const float* x = (const float*)d_in[0];
    const float* W = (const float*)d_in[1];
    const float* b = (const float*)d_in[2];
    const int* npadd = (const int*)d_in[3];
    float* out = (float*)d_out;

    char* ws = (char*)d_ws;
    // layout (120 MB used):
    __bf16* xb = (__bf16*)(ws);                          // 16 MB [0,16)
    __bf16* Wt = (__bf16*)(ws + (16ull << 20));          // 24 MB [16,40)
    __bf16* qb = (__bf16*)(ws + (40ull << 20));          // 16 MB [40,56)
    __bf16* kb = (__bf16*)(ws + (56ull << 20));          // 16 MB [56,72)
    __bf16* vT = (__bf16*)(ws + (72ull << 20));          // 16 MB [72,88)
    __bf16* S  = (__bf16*)(ws + (88ull << 20));          // 32 MB [88,120)
    __bf16* P  = (__bf16*)(ws + (40ull << 20));          // 32 MB reuse qb+kb

    cast_x_kernel<<<2048, 256, 0, stream>>>(x, xb, (T_DIM * C_DIM) / 4);
    transpose_w_kernel<<<dim3(N3 / 32, C_DIM / 32), dim3(32, 8), 0, stream>>>(W, Wt);
    qkv_gemm_kernel<<<dim3(T_DIM / 128, N3 / 128), 256, 0, stream>>>(xb, Wt, b,
                                                                     qb, kb, vT);
    sc_gemm_kernel<<<528, 256, 0, stream>>>(qb, kb, S);
    softmax_kernel<<<T_DIM, 256, 0, stream>>>(S, P, npadd);
    pv_gemm_kernel<<<512, 256, 0, stream>>>(P, vT, out);
}

// Round 6
// 376.802 us; speedup vs baseline: 1.1214x; 1.1064x over previous
//
#include <hip/hip_runtime.h>
#include <cstdint>

// ---------------------------------------------------------------------------
// PaddedSoftmaxSHCSA: y = softmax(mask(scale * (xW+b)_q @ (xW+b)_k^T)) @ (xW+b)_v
// T=4096, C=2048, NF=2048, 3*NF=6144. fp32 in/out, bf16 MFMA compute.
//
// Round 6 changes:
//  * GEMM core BK=32 -> BK=64: 32 MFMA + 16 ds_read per barrier pair (was 16+8)
//    — halves barrier/drain events per MFMA (AITER cadence is ~32 MFMA/barrier).
//    LDS 32 KB/block (5 blocks/CU LDS-limit; VGPR stays the binding limit, so
//    occupancy unchanged). NOT m132's BK=128 (64 KB LDS occupancy cliff).
//  * 8-chunk XOR swizzle: phys_chunk = log_chunk ^ (row&7); 2-way (free) banks.
//  * softmax: one wave per row, zero __syncthreads (was 2 barriers + LDS).
//  * sc: early-exit tiles fully inside padding (softmax masks unread bytes).
//  * pv: skip K-tiles fully below npadd (P cols < npadd are identically 0).
// Keep: 16x16x32 MFMA (32x32 re-conflicts: R4), all-frags preload (R3),
// triangular sc grid, balanced pv map, bf16 S.
// ---------------------------------------------------------------------------

#define T_DIM 4096
#define C_DIM 2048
#define NF    2048
#define N3    6144
#define NEGV  (-1e30f)

typedef __bf16 bf16x8 __attribute__((ext_vector_type(8)));
typedef __bf16 bf16x4 __attribute__((ext_vector_type(4)));
typedef float  f32x4  __attribute__((ext_vector_type(4)));

__device__ __forceinline__ void async_cp16(const void* g, void* l) {
    __builtin_amdgcn_global_load_lds(
        reinterpret_cast<const __attribute__((address_space(1))) unsigned int*>(
            reinterpret_cast<uintptr_t>(g)),
        reinterpret_cast<__attribute__((address_space(3))) unsigned int*>(
            reinterpret_cast<uintptr_t>(l)),
        16, 0, 0);
}

// Shared 128x128-tile GEMM K-loop, BK=64: C[m0..+128, n0..+128] += A @ B^T
// A: (M x K) row-major, lda elems; B: (N x K) row-major, ldb elems.
// LDS: 128 rows x 64 elems (128 B), 8 x 16B chunks/row, XOR-swizzled
// phys_chunk = log_chunk ^ (row & 7). Staging permutes the per-lane GLOBAL
// source chunk (global_load_lds dest is fixed at wavebase + lane*16).
// Two 16x16x32 MFMA k-steps per staged tile; 32 MFMA per barrier pair.
__device__ __forceinline__ void gemm_loop(const __bf16* A, const __bf16* B,
                                          int lda, int ldb, int m0, int n0,
                                          int kiters, __bf16* As, __bf16* Bs,
                                          f32x4 (&acc)[4][4]) {
    const int t    = threadIdx.x;          // 0..255
    const int wv   = t >> 6;               // wave 0..3
    const int lane = t & 63;
    const int srow = t >> 3;               // staging row 0..31 (issue 0)
    const int scol = (((t & 7) ^ (srow & 7)) << 3);  // logical col for my slot
    const int wm   = (wv >> 1) << 6;       // wave m offset 0/64
    const int wn   = (wv & 1) << 6;        // wave n offset 0/64
    const int lrow = lane & 15;
    const int kq   = lane >> 4;            // logical chunk within k-step 0..3
    const int swz  = lrow & 7;             // 16/32/64 row offsets preserve &7
    const int rc0  = ((kq ^ swz) << 3);         // k-step 0: chunks 0..3
    const int rc1  = (((kq | 4) ^ swz) << 3);   // k-step 1: chunks 4..7

    const __bf16* ga = A + (size_t)(m0 + srow) * lda + scol;
    const __bf16* gb = B + (size_t)(n0 + srow) * ldb + scol;

    for (int kk = 0; kk < kiters; ++kk) {
        // stage A,B tiles (128x64 = 16 KB each): 4 issues of 32 rows each
#pragma unroll
        for (int i = 0; i < 4; ++i) {
            async_cp16(ga + (size_t)(32 * i) * lda, &As[i * 2048 + wv * 512]);
            async_cp16(gb + (size_t)(32 * i) * ldb, &Bs[i * 2048 + wv * 512]);
        }
        ga += 64; gb += 64;
        __syncthreads();   // vmcnt(0) drain + barrier

#pragma unroll
        for (int kb = 0; kb < 2; ++kb) {
            const int rc = kb ? rc1 : rc0;
            bf16x8 af[4], bfr[4];
#pragma unroll
            for (int mi = 0; mi < 4; ++mi)
                af[mi] = *(const bf16x8*)&As[(wm + mi * 16 + lrow) * 64 + rc];
#pragma unroll
            for (int ni = 0; ni < 4; ++ni)
                bfr[ni] = *(const bf16x8*)&Bs[(wn + ni * 16 + lrow) * 64 + rc];
#pragma unroll
            for (int mi = 0; mi < 4; ++mi)
#pragma unroll
                for (int ni = 0; ni < 4; ++ni)
                    acc[mi][ni] = __builtin_amdgcn_mfma_f32_16x16x32_bf16(
                        af[mi], bfr[ni], acc[mi][ni], 0, 0, 0);
        }
        __syncthreads();   // protect LDS before next-iter staging overwrite
    }
}

// ---------------- 1. cast x -> bf16 ----------------
__global__ void cast_x_kernel(const float* __restrict__ x,
                              __bf16* __restrict__ xb, int n4) {
    int stride = gridDim.x * blockDim.x;
    for (int i = blockIdx.x * blockDim.x + threadIdx.x; i < n4; i += stride) {
        float4 v = ((const float4*)x)[i];
        bf16x4 o;
        o[0] = (__bf16)v.x; o[1] = (__bf16)v.y;
        o[2] = (__bf16)v.z; o[3] = (__bf16)v.w;
        ((bf16x4*)xb)[i] = o;
    }
}

// ---------------- 2. transpose-cast W (2048x6144) -> Wt (6144x2048) --------
__global__ void transpose_w_kernel(const float* __restrict__ W,
                                   __bf16* __restrict__ Wt) {
    __shared__ float tile[32][33];
    int bx = blockIdx.x * 32;  // W col / Wt row
    int by = blockIdx.y * 32;  // W row / Wt col
    int tx = threadIdx.x, ty = threadIdx.y;  // (32,8)
#pragma unroll
    for (int i = 0; i < 32; i += 8)
        tile[ty + i][tx] = W[(size_t)(by + ty + i) * N3 + bx + tx];
    __syncthreads();
#pragma unroll
    for (int i = 0; i < 32; i += 8)
        Wt[(size_t)(bx + ty + i) * C_DIM + by + tx] = (__bf16)tile[tx][ty + i];
}

// epilogue helpers for 16x16 C/D: col=lane&15, row=(lane>>4)*4+r
#define EPILOG_SETUP()                                     \
    const int t = threadIdx.x, wv = t >> 6, lane = t & 63; \
    const int wm = (wv >> 1) << 6, wn = (wv & 1) << 6;     \
    const int rq = (lane >> 4) << 2, cn = lane & 15

// ---------------- 3. QKV GEMM ----------------
__global__ void __launch_bounds__(256)
qkv_gemm_kernel(const __bf16* __restrict__ xb, const __bf16* __restrict__ Wt,
                const float* __restrict__ bias, __bf16* __restrict__ qb,
                __bf16* __restrict__ kb, __bf16* __restrict__ vT) {
    __shared__ __bf16 As[128 * 64];
    __shared__ __bf16 Bs[128 * 64];
    f32x4 acc[4][4] = {};
    const int m0 = blockIdx.x * 128, n0 = blockIdx.y * 128;
    gemm_loop(xb, Wt, C_DIM, C_DIM, m0, n0, C_DIM / 64, As, Bs, acc);

    EPILOG_SETUP();
#pragma unroll
    for (int mi = 0; mi < 4; ++mi)
#pragma unroll
        for (int ni = 0; ni < 4; ++ni) {
            int col = n0 + wn + ni * 16 + cn;
            float bv = bias[col];
#pragma unroll
            for (int r = 0; r < 4; ++r) {
                int row = m0 + wm + mi * 16 + rq + r;
                float val = acc[mi][ni][r] + bv;
                if (col < NF)
                    qb[(size_t)row * NF + col] = (__bf16)val;
                else if (col < 2 * NF)
                    kb[(size_t)row * NF + (col - NF)] = (__bf16)val;
                else
                    vT[(size_t)(col - 2 * NF) * T_DIM + row] = (__bf16)val;
            }
        }
}

// ---------------- 4. S = scale * q @ k^T (bf16; mask applied in softmax) ---
// Grid = 528 lower-triangle 128x128 tiles. Tiles fully inside the padding
// band (rows or cols entirely < npadd) are never read meaningfully by
// softmax (it masks them) -> skip.
__global__ void __launch_bounds__(256)
sc_gemm_kernel(const __bf16* __restrict__ qb, const __bf16* __restrict__ kb,
               __bf16* __restrict__ S, const int* __restrict__ npadd_p) {
    int i = blockIdx.x;
    int mt = (int)((sqrtf(8.0f * (float)i + 1.0f) - 1.0f) * 0.5f);
    while ((mt + 1) * (mt + 2) / 2 <= i) ++mt;
    while (mt * (mt + 1) / 2 > i) --mt;
    int nt = i - mt * (mt + 1) / 2;
    const int m0 = mt * 128, n0 = nt * 128;
    const int npadd = *npadd_p;
    if (m0 + 128 <= npadd || n0 + 128 <= npadd) return;  // fully masked

    __shared__ __bf16 As[128 * 64];
    __shared__ __bf16 Bs[128 * 64];
    f32x4 acc[4][4] = {};
    gemm_loop(qb, kb, NF, NF, m0, n0, NF / 64, As, Bs, acc);

    const float scale = 0.022097086912079608f;  // 1/sqrt(2048)
    EPILOG_SETUP();
#pragma unroll
    for (int mi = 0; mi < 4; ++mi)
#pragma unroll
        for (int ni = 0; ni < 4; ++ni) {
            int j = n0 + wn + ni * 16 + cn;
#pragma unroll
            for (int r = 0; r < 4; ++r) {
                int row = m0 + wm + mi * 16 + rq + r;
                S[(size_t)row * T_DIM + j] = (__bf16)(acc[mi][ni][r] * scale);
            }
        }
}

// ---------------- 5. row softmax: one WAVE per row, no barriers ------------
__global__ void __launch_bounds__(256)
softmax_kernel(const __bf16* __restrict__ S, __bf16* __restrict__ P,
               const int* __restrict__ npadd_p) {
    const int wv = threadIdx.x >> 6, lane = threadIdx.x & 63;
    const int row = blockIdx.x * 4 + wv;
    const int npadd = *npadd_p;
    __bf16* prow = P + (size_t)row * T_DIM;

    if (row < npadd) {  // padding row: p == 0
        bf16x8 z = {};
#pragma unroll
        for (int c = 0; c < 8; ++c) ((bf16x8*)prow)[c * 64 + lane] = z;
        return;
    }

    const __bf16* srow = S + (size_t)row * T_DIM;
    float vals[64];
    float mx = NEGV;
#pragma unroll
    for (int c = 0; c < 8; ++c) {
        if (c * 512 > row) {  // wave-uniform skip
#pragma unroll
            for (int e = 0; e < 8; ++e) vals[c * 8 + e] = NEGV;
            continue;
        }
        int j0 = c * 512 + lane * 8;
        bf16x8 v = ((const bf16x8*)srow)[c * 64 + lane];
#pragma unroll
        for (int e = 0; e < 8; ++e) {
            float f = (j0 + e >= npadd && j0 + e <= row) ? (float)v[e] : NEGV;
            vals[c * 8 + e] = f;
            mx = fmaxf(mx, f);
        }
    }
#pragma unroll
    for (int o = 32; o > 0; o >>= 1) mx = fmaxf(mx, __shfl_xor(mx, o));

    float sm = 0.f;
#pragma unroll
    for (int k = 0; k < 64; ++k) {
        vals[k] = exp2f((vals[k] - mx) * 1.4426950408889634f);
        sm += vals[k];
    }
#pragma unroll
    for (int o = 32; o > 0; o >>= 1) sm += __shfl_xor(sm, o);
    float inv = 1.0f / sm;

#pragma unroll
    for (int c = 0; c < 8; ++c) {
        bf16x8 o;
#pragma unroll
        for (int e = 0; e < 8; ++e) o[e] = (__bf16)(vals[c * 8 + e] * inv);
        ((bf16x8*)prow)[c * 64 + lane] = o;
    }
}

// ---------------- 6. y = P @ V ----------------
// Flat grid 512; same-CU pairs (idx, idx+256 under round-robin dispatch)
// get complementary m-tiles (m, 31-m) -> uniform K-work/CU. K-tiles fully
// below npadd are skipped (P cols < npadd are identically zero).
__global__ void __launch_bounds__(256)
pv_gemm_kernel(const __bf16* __restrict__ P, const __bf16* __restrict__ vT,
               float* __restrict__ out, const int* __restrict__ npadd_p) {
    const int idx = blockIdx.x;
    const int j = idx & 255, h = idx >> 8;
    int mt = j >> 3; if (h) mt = 31 - mt;
    const int nt = (j & 7) + (h << 3);
    const int m0 = mt * 128, n0 = nt * 128;
    const int kskip = *npadd_p >> 6;          // BK=64 tiles fully masked
    const int kiters = (mt + 1) * 2 - kskip;  // causal: P[i][j]=0 for j>i

    __shared__ __bf16 As[128 * 64];
    __shared__ __bf16 Bs[128 * 64];
    f32x4 acc[4][4] = {};
    gemm_loop(P + (size_t)kskip * 64, vT + (size_t)kskip * 64,
              T_DIM, T_DIM, m0, n0, kiters, As, Bs, acc);

    EPILOG_SETUP();
#pragma unroll
    for (int mi = 0; mi < 4; ++mi)
#pragma unroll
        for (int ni = 0; ni < 4; ++ni) {
            int col = n0 + wn + ni * 16 + cn;
#pragma unroll
            for (int r = 0; r < 4; ++r) {
                int row = m0 + wm + mi * 16 + rq + r;
                out[(size_t)row * NF + col] = acc[mi][ni][r];
            }
        }
}

extern "C" void kernel_launch(void* const* d_in, const int* in_sizes, int n_in,
                              void* d_out, int out_size, void* d_ws,
                              size_t ws_size, hipStream_t stream) {
    const float* x = (const float*)d_in[0];
    const float* W = (const float*)d_in[1];
    const float* b = (const float*)d_in[2];
    const int* npadd = (const int*)d_in[3];
    float* out = (float*)d_out;

    char* ws = (char*)d_ws;
    // layout (120 MB used):
    __bf16* xb = (__bf16*)(ws);                          // 16 MB [0,16)
    __bf16* Wt = (__bf16*)(ws + (16ull << 20));          // 24 MB [16,40)
    __bf16* qb = (__bf16*)(ws + (40ull << 20));          // 16 MB [40,56)
    __bf16* kb = (__bf16*)(ws + (56ull << 20));          // 16 MB [56,72)
    __bf16* vT = (__bf16*)(ws + (72ull << 20));          // 16 MB [72,88)
    __bf16* S  = (__bf16*)(ws + (88ull << 20));          // 32 MB [88,120)
    __bf16* P  = (__bf16*)(ws + (40ull << 20));          // 32 MB reuse qb+kb

    cast_x_kernel<<<2048, 256, 0, stream>>>(x, xb, (T_DIM * C_DIM) / 4);
    transpose_w_kernel<<<dim3(N3 / 32, C_DIM / 32), dim3(32, 8), 0, stream>>>(W, Wt);
    qkv_gemm_kernel<<<dim3(T_DIM / 128, N3 / 128), 256, 0, stream>>>(xb, Wt, b,
                                                                     qb, kb, vT);
    sc_gemm_kernel<<<528, 256, 0, stream>>>(qb, kb, S, npadd);
    softmax_kernel<<<T_DIM / 4, 256, 0, stream>>>(S, P, npadd);
    pv_gemm_kernel<<<512, 256, 0, stream>>>(P, vT, out, npadd);
}

// Round 7
// 354.113 us; speedup vs baseline: 1.1933x; 1.0641x over previous
//
#include <hip/hip_runtime.h>
#include <cstdint>

// ---------------------------------------------------------------------------
// PaddedSoftmaxSHCSA: y = softmax(mask(scale * (xW+b)_q @ (xW+b)_k^T)) @ (xW+b)_v
// T=4096, C=2048, NF=2048, 3*NF=6144. fp32 in/out, bf16 MFMA compute.
//
// Round 7 changes (makespan attack — R6 showed ~100 us of packing loss vs the
// 0.70 us/iter/CU pipe rate, dominated by pv's 62-iter straggler blocks):
//  * pv split-K: mt>=16 output tiles computed by TWO blocks (k-halves, max
//    ~31 iters each; grid 768 = 3/CU). Half-blocks unsafeAtomicAdd (native
//    global_atomic_add_f32) onto rows>=2048 zeroed via hipMemsetAsync.
//  * prep kernel = cast_x + transpose_W merged (one launch, co-resident).
//  * QKV epilogue: vT stores vectorized bf16x4 (r=0..3 contiguous in vT).
// Keep: BK=64 core w/ 8-chunk XOR swizzle (0 conflicts), 16x16x32 MFMA,
// all-frags preload, triangular sc grid, bf16 S, wave-per-row softmax.
// ---------------------------------------------------------------------------

#define T_DIM 4096
#define C_DIM 2048
#define NF    2048
#define N3    6144
#define NEGV  (-1e30f)

typedef __bf16 bf16x8 __attribute__((ext_vector_type(8)));
typedef __bf16 bf16x4 __attribute__((ext_vector_type(4)));
typedef float  f32x4  __attribute__((ext_vector_type(4)));

__device__ __forceinline__ void async_cp16(const void* g, void* l) {
    __builtin_amdgcn_global_load_lds(
        reinterpret_cast<const __attribute__((address_space(1))) unsigned int*>(
            reinterpret_cast<uintptr_t>(g)),
        reinterpret_cast<__attribute__((address_space(3))) unsigned int*>(
            reinterpret_cast<uintptr_t>(l)),
        16, 0, 0);
}

// Shared 128x128-tile GEMM K-loop, BK=64: C[m0..+128, n0..+128] += A @ B^T
// A: (M x K) row-major, lda elems; B: (N x K) row-major, ldb elems.
// LDS: 128 rows x 64 elems, 8 x 16B chunks/row, XOR-swizzled
// phys_chunk = log_chunk ^ (row & 7); staging permutes per-lane GLOBAL source
// chunk (global_load_lds dest fixed at wavebase + lane*16). 32 MFMA/barrier.
__device__ __forceinline__ void gemm_loop(const __bf16* A, const __bf16* B,
                                          int lda, int ldb, int m0, int n0,
                                          int kiters, __bf16* As, __bf16* Bs,
                                          f32x4 (&acc)[4][4]) {
    const int t    = threadIdx.x;          // 0..255
    const int wv   = t >> 6;               // wave 0..3
    const int lane = t & 63;
    const int srow = t >> 3;               // staging row 0..31 (issue 0)
    const int scol = (((t & 7) ^ (srow & 7)) << 3);  // logical col for my slot
    const int wm   = (wv >> 1) << 6;       // wave m offset 0/64
    const int wn   = (wv & 1) << 6;        // wave n offset 0/64
    const int lrow = lane & 15;
    const int kq   = lane >> 4;            // logical chunk within k-step 0..3
    const int swz  = lrow & 7;             // 16/32/64 row offsets preserve &7
    const int rc0  = ((kq ^ swz) << 3);         // k-step 0: chunks 0..3
    const int rc1  = (((kq | 4) ^ swz) << 3);   // k-step 1: chunks 4..7

    const __bf16* ga = A + (size_t)(m0 + srow) * lda + scol;
    const __bf16* gb = B + (size_t)(n0 + srow) * ldb + scol;

    for (int kk = 0; kk < kiters; ++kk) {
        // stage A,B tiles (128x64 = 16 KB each): 4 issues of 32 rows each
#pragma unroll
        for (int i = 0; i < 4; ++i) {
            async_cp16(ga + (size_t)(32 * i) * lda, &As[i * 2048 + wv * 512]);
            async_cp16(gb + (size_t)(32 * i) * ldb, &Bs[i * 2048 + wv * 512]);
        }
        ga += 64; gb += 64;
        __syncthreads();   // vmcnt(0) drain + barrier

#pragma unroll
        for (int kb = 0; kb < 2; ++kb) {
            const int rc = kb ? rc1 : rc0;
            bf16x8 af[4], bfr[4];
#pragma unroll
            for (int mi = 0; mi < 4; ++mi)
                af[mi] = *(const bf16x8*)&As[(wm + mi * 16 + lrow) * 64 + rc];
#pragma unroll
            for (int ni = 0; ni < 4; ++ni)
                bfr[ni] = *(const bf16x8*)&Bs[(wn + ni * 16 + lrow) * 64 + rc];
#pragma unroll
            for (int mi = 0; mi < 4; ++mi)
#pragma unroll
                for (int ni = 0; ni < 4; ++ni)
                    acc[mi][ni] = __builtin_amdgcn_mfma_f32_16x16x32_bf16(
                        af[mi], bfr[ni], acc[mi][ni], 0, 0, 0);
        }
        __syncthreads();   // protect LDS before next-iter staging overwrite
    }
}

// ---------------- 1. prep: cast x -> bf16  AND  transpose-cast W -----------
// blocks [0,2048): grid-stride float4 cast of x (4096x2048).
// blocks [2048,14336): 32x32 tile transpose of W (2048x6144) -> Wt (6144x2048).
__global__ void prep_kernel(const float* __restrict__ x,
                            __bf16* __restrict__ xb,
                            const float* __restrict__ W,
                            __bf16* __restrict__ Wt) {
    if (blockIdx.x < 2048) {
        const int n4 = (T_DIM * C_DIM) / 4;
        const int stride = 2048 * 256;
        for (int i = blockIdx.x * 256 + threadIdx.x; i < n4; i += stride) {
            float4 v = ((const float4*)x)[i];
            bf16x4 o;
            o[0] = (__bf16)v.x; o[1] = (__bf16)v.y;
            o[2] = (__bf16)v.z; o[3] = (__bf16)v.w;
            ((bf16x4*)xb)[i] = o;
        }
        return;
    }
    __shared__ float tile[32][33];
    const int tb = blockIdx.x - 2048;
    const int bx = (tb % (N3 / 32)) * 32;  // W col / Wt row
    const int by = (tb / (N3 / 32)) * 32;  // W row / Wt col
    const int tx = threadIdx.x & 31, ty = threadIdx.x >> 5;  // (32,8)
#pragma unroll
    for (int i = 0; i < 32; i += 8)
        tile[ty + i][tx] = W[(size_t)(by + ty + i) * N3 + bx + tx];
    __syncthreads();
#pragma unroll
    for (int i = 0; i < 32; i += 8)
        Wt[(size_t)(bx + ty + i) * C_DIM + by + tx] = (__bf16)tile[tx][ty + i];
}

// epilogue helpers for 16x16 C/D: col=lane&15, row=(lane>>4)*4+r
#define EPILOG_SETUP()                                     \
    const int t = threadIdx.x, wv = t >> 6, lane = t & 63; \
    const int wm = (wv >> 1) << 6, wn = (wv & 1) << 6;     \
    const int rq = (lane >> 4) << 2, cn = lane & 15

// ---------------- 3. QKV GEMM ----------------
__global__ void __launch_bounds__(256)
qkv_gemm_kernel(const __bf16* __restrict__ xb, const __bf16* __restrict__ Wt,
                const float* __restrict__ bias, __bf16* __restrict__ qb,
                __bf16* __restrict__ kb, __bf16* __restrict__ vT) {
    __shared__ __bf16 As[128 * 64];
    __shared__ __bf16 Bs[128 * 64];
    f32x4 acc[4][4] = {};
    const int m0 = blockIdx.x * 128, n0 = blockIdx.y * 128;
    gemm_loop(xb, Wt, C_DIM, C_DIM, m0, n0, C_DIM / 64, As, Bs, acc);

    EPILOG_SETUP();
#pragma unroll
    for (int mi = 0; mi < 4; ++mi)
#pragma unroll
        for (int ni = 0; ni < 4; ++ni) {
            int col = n0 + wn + ni * 16 + cn;
            float bv = bias[col];
            if (col >= 2 * NF) {
                // vT rows r=0..3 are contiguous: one bf16x4 store
                bf16x4 o;
#pragma unroll
                for (int r = 0; r < 4; ++r) o[r] = (__bf16)(acc[mi][ni][r] + bv);
                int row = m0 + wm + mi * 16 + rq;
                *(bf16x4*)&vT[(size_t)(col - 2 * NF) * T_DIM + row] = o;
            } else {
#pragma unroll
                for (int r = 0; r < 4; ++r) {
                    int row = m0 + wm + mi * 16 + rq + r;
                    float val = acc[mi][ni][r] + bv;
                    if (col < NF)
                        qb[(size_t)row * NF + col] = (__bf16)val;
                    else
                        kb[(size_t)row * NF + (col - NF)] = (__bf16)val;
                }
            }
        }
}

// ---------------- 4. S = scale * q @ k^T (bf16; mask applied in softmax) ---
// Grid = 528 lower-triangle 128x128 tiles; padding-band tiles skipped.
__global__ void __launch_bounds__(256)
sc_gemm_kernel(const __bf16* __restrict__ qb, const __bf16* __restrict__ kb,
               __bf16* __restrict__ S, const int* __restrict__ npadd_p) {
    int i = blockIdx.x;
    int mt = (int)((sqrtf(8.0f * (float)i + 1.0f) - 1.0f) * 0.5f);
    while ((mt + 1) * (mt + 2) / 2 <= i) ++mt;
    while (mt * (mt + 1) / 2 > i) --mt;
    int nt = i - mt * (mt + 1) / 2;
    const int m0 = mt * 128, n0 = nt * 128;
    const int npadd = *npadd_p;
    if (m0 + 128 <= npadd || n0 + 128 <= npadd) return;  // fully masked

    __shared__ __bf16 As[128 * 64];
    __shared__ __bf16 Bs[128 * 64];
    f32x4 acc[4][4] = {};
    gemm_loop(qb, kb, NF, NF, m0, n0, NF / 64, As, Bs, acc);

    const float scale = 0.022097086912079608f;  // 1/sqrt(2048)
    EPILOG_SETUP();
#pragma unroll
    for (int mi = 0; mi < 4; ++mi)
#pragma unroll
        for (int ni = 0; ni < 4; ++ni) {
            int j = n0 + wn + ni * 16 + cn;
#pragma unroll
            for (int r = 0; r < 4; ++r) {
                int row = m0 + wm + mi * 16 + rq + r;
                S[(size_t)row * T_DIM + j] = (__bf16)(acc[mi][ni][r] * scale);
            }
        }
}

// ---------------- 5. row softmax: one WAVE per row, no barriers ------------
__global__ void __launch_bounds__(256)
softmax_kernel(const __bf16* __restrict__ S, __bf16* __restrict__ P,
               const int* __restrict__ npadd_p) {
    const int wv = threadIdx.x >> 6, lane = threadIdx.x & 63;
    const int row = blockIdx.x * 4 + wv;
    const int npadd = *npadd_p;
    __bf16* prow = P + (size_t)row * T_DIM;

    if (row < npadd) {  // padding row: p == 0
        bf16x8 z = {};
#pragma unroll
        for (int c = 0; c < 8; ++c) ((bf16x8*)prow)[c * 64 + lane] = z;
        return;
    }

    const __bf16* srow = S + (size_t)row * T_DIM;
    float vals[64];
    float mx = NEGV;
#pragma unroll
    for (int c = 0; c < 8; ++c) {
        if (c * 512 > row) {  // wave-uniform skip
#pragma unroll
            for (int e = 0; e < 8; ++e) vals[c * 8 + e] = NEGV;
            continue;
        }
        int j0 = c * 512 + lane * 8;
        bf16x8 v = ((const bf16x8*)srow)[c * 64 + lane];
#pragma unroll
        for (int e = 0; e < 8; ++e) {
            float f = (j0 + e >= npadd && j0 + e <= row) ? (float)v[e] : NEGV;
            vals[c * 8 + e] = f;
            mx = fmaxf(mx, f);
        }
    }
#pragma unroll
    for (int o = 32; o > 0; o >>= 1) mx = fmaxf(mx, __shfl_xor(mx, o));

    float sm = 0.f;
#pragma unroll
    for (int k = 0; k < 64; ++k) {
        vals[k] = exp2f((vals[k] - mx) * 1.4426950408889634f);
        sm += vals[k];
    }
#pragma unroll
    for (int o = 32; o > 0; o >>= 1) sm += __shfl_xor(sm, o);
    float inv = 1.0f / sm;

#pragma unroll
    for (int c = 0; c < 8; ++c) {
        bf16x8 o;
#pragma unroll
        for (int e = 0; e < 8; ++e) o[e] = (__bf16)(vals[c * 8 + e] * inv);
        ((bf16x8*)prow)[c * 64 + lane] = o;
    }
}

// ---------------- 6. y = P @ V, split-K for the deep tiles -----------------
// Grid 768: idx<256 -> single block for mt=idx&15 (<=30 iters, plain store);
// idx>=256 -> mt=16+(j&15), half=(j>>8): two blocks split the k-range
// (<=31 iters each) and unsafeAtomicAdd onto rows>=2048 (zeroed by memset).
__global__ void __launch_bounds__(256)
pv_gemm_kernel(const __bf16* __restrict__ P, const __bf16* __restrict__ vT,
               float* __restrict__ out, const int* __restrict__ npadd_p) {
    const int idx = blockIdx.x;
    const int kskip = *npadd_p >> 6;  // BK=64 tiles fully inside padding
    int mt, nt, start, iters;
    bool atomic_out;
    if (idx < 256) {
        mt = idx & 15; nt = idx >> 4;
        int kt = (mt + 1) * 2 - kskip; if (kt < 0) kt = 0;
        start = kskip; iters = kt; atomic_out = false;
    } else {
        int j = idx - 256;
        mt = 16 + (j & 15); nt = (j >> 4) & 15;
        int half = j >> 8;
        int kt = (mt + 1) * 2 - kskip; if (kt < 0) kt = 0;
        int h0 = (kt + 1) >> 1;
        start = kskip + (half ? h0 : 0);
        iters = half ? kt - h0 : h0;
        atomic_out = true;
    }
    const int m0 = mt * 128, n0 = nt * 128;

    __shared__ __bf16 As[128 * 64];
    __shared__ __bf16 Bs[128 * 64];
    f32x4 acc[4][4] = {};
    gemm_loop(P + (size_t)start * 64, vT + (size_t)start * 64,
              T_DIM, T_DIM, m0, n0, iters, As, Bs, acc);

    EPILOG_SETUP();
#pragma unroll
    for (int mi = 0; mi < 4; ++mi)
#pragma unroll
        for (int ni = 0; ni < 4; ++ni) {
            int col = n0 + wn + ni * 16 + cn;
#pragma unroll
            for (int r = 0; r < 4; ++r) {
                int row = m0 + wm + mi * 16 + rq + r;
                float* p = &out[(size_t)row * NF + col];
                if (atomic_out) unsafeAtomicAdd(p, acc[mi][ni][r]);
                else            *p = acc[mi][ni][r];
            }
        }
}

extern "C" void kernel_launch(void* const* d_in, const int* in_sizes, int n_in,
                              void* d_out, int out_size, void* d_ws,
                              size_t ws_size, hipStream_t stream) {
    const float* x = (const float*)d_in[0];
    const float* W = (const float*)d_in[1];
    const float* b = (const float*)d_in[2];
    const int* npadd = (const int*)d_in[3];
    float* out = (float*)d_out;

    char* ws = (char*)d_ws;
    // layout (120 MB used):
    __bf16* xb = (__bf16*)(ws);                          // 16 MB [0,16)
    __bf16* Wt = (__bf16*)(ws + (16ull << 20));          // 24 MB [16,40)
    __bf16* qb = (__bf16*)(ws + (40ull << 20));          // 16 MB [40,56)
    __bf16* kb = (__bf16*)(ws + (56ull << 20));          // 16 MB [56,72)
    __bf16* vT = (__bf16*)(ws + (72ull << 20));          // 16 MB [72,88)
    __bf16* S  = (__bf16*)(ws + (88ull << 20));          // 32 MB [88,120)
    __bf16* P  = (__bf16*)(ws + (40ull << 20));          // 32 MB reuse qb+kb

    // zero the atomic-accumulated half of out (rows 2048..4095)
    hipMemsetAsync(out + (size_t)2048 * NF, 0, (size_t)2048 * NF * 4, stream);

    prep_kernel<<<2048 + (N3 / 32) * (C_DIM / 32), 256, 0, stream>>>(x, xb, W, Wt);
    qkv_gemm_kernel<<<dim3(T_DIM / 128, N3 / 128), 256, 0, stream>>>(xb, Wt, b,
                                                                     qb, kb, vT);
    sc_gemm_kernel<<<528, 256, 0, stream>>>(qb, kb, S, npadd);
    softmax_kernel<<<T_DIM / 4, 256, 0, stream>>>(S, P, npadd);
    pv_gemm_kernel<<<768, 256, 0, stream>>>(P, vT, out, npadd);
}